// Round 6
// baseline (497.571 us; speedup 1.0000x reference)
//
#include <hip/hip_runtime.h>
#include <hip/hip_cooperative_groups.h>
#include <math.h>

namespace cg = cooperative_groups;

// LightGCN layer: out[v] = sum_{(u->v)} w * x[u], N=100K, E=1.6M, D=128, fp32.
//
// R14: R13 falsified the store-fragmentation theory (padding regressed).
// Front-end is ~123-153us across FOUR scatter designs -> insensitive to
// scatter structure; suspects are dispatch gaps / init / invisible-in-
// counters overhead. Fix + measurement in one move: FUSE init+scatter+gather
// into ONE cooperative kernel (nbk=782 blocks x 256 thr, 2x grid.sync()):
//   - all inter-dispatch gaps + init dispatch eliminated
//   - scatter phase on 782 blocks (vs 128/256) = 6x CU coverage
//   - csr written then read in-kernel -> L2/LLC-warm for gather
//   - single dispatch = full counter attribution next round
// Gather body frozen (R8/R12-proven rate-saturated ~3.4 TB/s on random
// 512B row fills). Fallbacks: R12 3-dispatch seg path if cooperative launch
// rejected; exact-CSR path for small ws; atomic fallback last.

constexpr int D_FEAT = 128;
constexpr int NPB = 128;        // nodes per bucket (dst >> 7)
constexpr int LOG_NPB = 7;
constexpr int NBK_MAX = 1024;
constexpr int SCB = 256;        // separate-path scatter/hist block count
constexpr int CAP = 3072;       // max edges per bucket staged in gather LDS

typedef float v4f __attribute__((ext_vector_type(4)));

// ---------------- fallback (R1) ----------------
__global__ __launch_bounds__(256) void scatter_atomic_kernel(
    const float* __restrict__ x, const float* __restrict__ w,
    const int* __restrict__ src_idx, const int* __restrict__ dst_idx,
    float* __restrict__ out, int n_edges) {
  long long tid = (long long)blockIdx.x * blockDim.x + threadIdx.x;
  int lane = (int)(tid & 31);
  long long e = tid >> 5;
  if (e >= n_edges) return;
  int s = src_idx[e];
  int d = dst_idx[e];
  float wt = w[e];
  float4 v = ((const float4*)(x + (size_t)s * D_FEAT))[lane];
  float* o = out + (size_t)d * D_FEAT + (size_t)lane * 4;
  atomicAdd(o + 0, v.x * wt);
  atomicAdd(o + 1, v.y * wt);
  atomicAdd(o + 2, v.z * wt);
  atomicAdd(o + 3, v.w * wt);
}

// block-wide exclusive scan over blockDim.x threads (multiple of 64, <=512);
// sh holds >= (nwaves+1) ints (declare 9).
__device__ __forceinline__ int block_excl_scan(int v, int* sh, int* total) {
  const int lane = threadIdx.x & 63;
  const int wid = threadIdx.x >> 6;
  const int nw = blockDim.x >> 6;
  int inc = v;
  #pragma unroll
  for (int o = 1; o < 64; o <<= 1) {
    int t = __shfl_up(inc, o, 64);
    if (lane >= o) inc += t;
  }
  if (lane == 63) sh[wid] = inc;
  __syncthreads();
  if (threadIdx.x == 0) {
    int a = 0;
    for (int k = 0; k < nw; ++k) { int t = sh[k]; sh[k] = a; a += t; }
    sh[nw] = a;
  }
  __syncthreads();
  int r = sh[wid] + inc - v;
  if (total) *total = sh[nw];
  __syncthreads();
  return r;
}

// ================= FUSED cooperative kernel (segment mode) =================
// grid = nbk blocks x 256 thr. Phases: init gcur -> sync -> scatter tile ->
// sync -> gather bucket. LDS: union of scatter arrays (12KB) and gather
// arrays (~31.5KB) -> 4 blocks/CU co-resident (782 <= 1024 capacity).
__global__ __launch_bounds__(256) void fused_kernel(
    const float* __restrict__ x, const float* __restrict__ w,
    const int* __restrict__ src, const int* __restrict__ dst,
    int* __restrict__ gcur, uint2* __restrict__ csr,
    float* __restrict__ out, int n_edges, int n_nodes, int nbk, int tile,
    int capb) {
  __shared__ union SM {
    struct { int h[NBK_MAX]; int cur[NBK_MAX]; int gb[NBK_MAX]; } sc;
    struct {
      uint2 eds[CAP];
      unsigned short perm[CAP];
      int loff[NPB + 1];
      int lcur[NPB];
      int sh[9];
    } ga;
  } sm;
  cg::grid_group grid = cg::this_grid();
  const int tid = threadIdx.x;
  const int b = blockIdx.x;

  // ---- phase 0: init (one gcur entry per block; grid == nbk) ----
  if (tid == 0) gcur[b] = b * capb;
  for (int k = tid; k < nbk; k += 256) sm.sc.h[k] = 0;
  __syncthreads();
  grid.sync();

  // ---- phase 1: scatter my tile ----
  int base = b * tile;
  int lim = min(base + tile, n_edges);
  for (int i = base + tid; i < lim; i += 256)
    atomicAdd(&sm.sc.h[((unsigned)dst[i]) >> LOG_NPB], 1);
  __syncthreads();
  for (int k = tid; k < nbk; k += 256) {
    sm.sc.cur[k] = 0;
    int v = sm.sc.h[k];
    int g = -1;
    if (v) {
      g = atomicAdd(&gcur[k], v);
      if (g + v > (k + 1) * capb) g = -1;  // overflow: drop run (P ~ 1e-6)
    }
    sm.sc.gb[k] = g;
  }
  __syncthreads();
  for (int i = base + tid; i < lim; i += 256) {
    unsigned d = (unsigned)dst[i];
    unsigned k = d >> LOG_NPB;
    int pos = atomicAdd(&sm.sc.cur[k], 1);
    int g = sm.sc.gb[k];
    if (g >= 0)
      csr[g + pos] = make_uint2((unsigned)src[i] | ((d & (NPB - 1u)) << 20),
                                __float_as_uint(w[i]));
  }
  __threadfence();
  grid.sync();

  // ---- phase 2: gather bucket b (frozen R8 body) ----
  const int beg = b * capb;
  const int cnt = gcur[b] - beg;
  const int nbase = b * NPB;
  const int wv = tid >> 6;
  const int lane = tid & 63;
  const int f = lane & 31;
  const int half = lane >> 5;
  const float4* X = (const float4*)x;

  if (cnt <= capb) {
    if (tid < NPB) sm.ga.lcur[tid] = 0;
    __syncthreads();
    for (int i = tid; i < cnt; i += 256) {
      uint2 e = csr[beg + i];
      sm.ga.eds[i] = e;
      atomicAdd(&sm.ga.lcur[e.x >> 20], 1);
    }
    __syncthreads();
    {
      int v = (tid < NPB) ? sm.ga.lcur[tid] : 0;
      int ex = block_excl_scan(v, sm.ga.sh, nullptr);
      __syncthreads();
      if (tid < NPB) { sm.ga.loff[tid] = ex; sm.ga.lcur[tid] = 0; }
      if (tid == 0) sm.ga.loff[NPB] = cnt;
    }
    __syncthreads();
    for (int i = tid; i < cnt; i += 256) {
      int dl = sm.ga.eds[i].x >> 20;
      int pos = sm.ga.loff[dl] + atomicAdd(&sm.ga.lcur[dl], 1);
      sm.ga.perm[pos] = (unsigned short)i;
    }
    __syncthreads();

    for (int n = wv; n < NPB; n += 4) {
      int node = nbase + n;
      if (node >= n_nodes) break;
      int jb = sm.ga.loff[n];
      int je = sm.ga.loff[n + 1];
      float4 a0 = make_float4(0.f, 0.f, 0.f, 0.f);
      float4 a1 = make_float4(0.f, 0.f, 0.f, 0.f);
      float4 a2 = make_float4(0.f, 0.f, 0.f, 0.f);
      float4 a3 = make_float4(0.f, 0.f, 0.f, 0.f);
      int j = jb + half;
      for (; j + 6 < je; j += 8) {
        uint2 e0 = sm.ga.eds[sm.ga.perm[j]];
        uint2 e1 = sm.ga.eds[sm.ga.perm[j + 2]];
        uint2 e2 = sm.ga.eds[sm.ga.perm[j + 4]];
        uint2 e3 = sm.ga.eds[sm.ga.perm[j + 6]];
        float4 v0 = X[(size_t)(e0.x & 0xFFFFFu) * 32 + f];
        float4 v1 = X[(size_t)(e1.x & 0xFFFFFu) * 32 + f];
        float4 v2 = X[(size_t)(e2.x & 0xFFFFFu) * 32 + f];
        float4 v3 = X[(size_t)(e3.x & 0xFFFFFu) * 32 + f];
        float w0 = __uint_as_float(e0.y);
        float w1 = __uint_as_float(e1.y);
        float w2 = __uint_as_float(e2.y);
        float w3 = __uint_as_float(e3.y);
        a0.x += w0 * v0.x; a0.y += w0 * v0.y; a0.z += w0 * v0.z; a0.w += w0 * v0.w;
        a1.x += w1 * v1.x; a1.y += w1 * v1.y; a1.z += w1 * v1.z; a1.w += w1 * v1.w;
        a2.x += w2 * v2.x; a2.y += w2 * v2.y; a2.z += w2 * v2.z; a2.w += w2 * v2.w;
        a3.x += w3 * v3.x; a3.y += w3 * v3.y; a3.z += w3 * v3.z; a3.w += w3 * v3.w;
      }
      for (; j < je; j += 2) {
        uint2 e0 = sm.ga.eds[sm.ga.perm[j]];
        float4 v0 = X[(size_t)(e0.x & 0xFFFFFu) * 32 + f];
        float w0 = __uint_as_float(e0.y);
        a0.x += w0 * v0.x; a0.y += w0 * v0.y; a0.z += w0 * v0.z; a0.w += w0 * v0.w;
      }
      a0.x += a1.x + a2.x + a3.x;
      a0.y += a1.y + a2.y + a3.y;
      a0.z += a1.z + a2.z + a3.z;
      a0.w += a1.w + a2.w + a3.w;
      a0.x += __shfl_xor(a0.x, 32, 64);
      a0.y += __shfl_xor(a0.y, 32, 64);
      a0.z += __shfl_xor(a0.z, 32, 64);
      a0.w += __shfl_xor(a0.w, 32, 64);
      if (half == 0) {
        v4f val = {a0.x, a0.y, a0.z, a0.w};
        __builtin_nontemporal_store(val, (v4f*)out + (size_t)node * 32 + f);
      }
    }
  } else {
    // overflow safety net: scan raw edge list for this bucket's nodes
    for (int n = wv; n < NPB; n += 4) {
      int node = nbase + n;
      if (node >= n_nodes) break;
      float4 a0 = make_float4(0.f, 0.f, 0.f, 0.f);
      for (int j = half; j < n_edges; j += 2) {
        if (dst[j] == node) {
          float4 v = X[(size_t)src[j] * 32 + f];
          float wt = w[j];
          a0.x += wt * v.x; a0.y += wt * v.y; a0.z += wt * v.z; a0.w += wt * v.w;
        }
      }
      a0.x += __shfl_xor(a0.x, 32, 64);
      a0.y += __shfl_xor(a0.y, 32, 64);
      a0.z += __shfl_xor(a0.z, 32, 64);
      a0.w += __shfl_xor(a0.w, 32, 64);
      if (half == 0) {
        v4f val = {a0.x, a0.y, a0.z, a0.w};
        __builtin_nontemporal_store(val, (v4f*)out + (size_t)node * 32 + f);
      }
    }
  }
}

// ================= separate-dispatch fallback path (R12) ===================

// exact path phase 1: global hist + in-kernel prefix (last block does it)
__global__ __launch_bounds__(512) void hist_kernel(
    const int* __restrict__ dst, int* __restrict__ gtot,
    int* __restrict__ gcur, int* __restrict__ gbase, int* __restrict__ done,
    int n_edges, int nbk, int tile) {
  __shared__ int h[NBK_MAX];
  __shared__ int sh[9];
  __shared__ int slast;
  const int tid = threadIdx.x;
  const int b = blockIdx.x;
  for (int k = tid; k < nbk; k += 512) h[k] = 0;
  __syncthreads();
  int base = b * tile;
  int lim = min(base + tile, n_edges);
  for (int i = base + tid; i < lim; i += 512)
    atomicAdd(&h[((unsigned)dst[i]) >> LOG_NPB], 1);
  __syncthreads();
  for (int k = tid; k < nbk; k += 512)
    if (h[k]) atomicAdd(&gtot[k], h[k]);
  __threadfence();
  __syncthreads();
  if (tid == 0)
    slast = (__hip_atomic_fetch_add(done, 1, __ATOMIC_ACQ_REL,
                                    __HIP_MEMORY_SCOPE_AGENT) ==
             (int)gridDim.x - 1);
  __syncthreads();
  if (slast) {
    int carry = 0;
    for (int kb = 0; kb < nbk; kb += 512) {
      int k = kb + tid;
      int v = (k < nbk)
                  ? __hip_atomic_load(&gtot[k], __ATOMIC_RELAXED,
                                      __HIP_MEMORY_SCOPE_AGENT)
                  : 0;
      int tot;
      int ex = block_excl_scan(v, sh, &tot);
      if (k < nbk) { gbase[k] = carry + ex; gcur[k] = carry + ex; }
      carry += tot;
    }
    if (tid == 0) gbase[nbk] = carry;
  }
}

__global__ __launch_bounds__(256) void init_seg_kernel(int* __restrict__ gcur,
                                                       int nbk, int capb) {
  int k = blockIdx.x * 256 + threadIdx.x;
  if (k < nbk) gcur[k] = k * capb;
}

__global__ __launch_bounds__(512) void scatter_kernel(
    const int* __restrict__ src, const int* __restrict__ dst,
    const float* __restrict__ w, int* __restrict__ gcur,
    uint2* __restrict__ csr, int n_edges, int nbk, int tile, int capb) {
  __shared__ int h[NBK_MAX];
  __shared__ int cur[NBK_MAX];
  __shared__ int gb[NBK_MAX];
  const int tid = threadIdx.x;
  const int b = blockIdx.x;
  int base = b * tile;
  int lim = min(base + tile, n_edges);
  for (int k = tid; k < nbk; k += 512) h[k] = 0;
  __syncthreads();
  for (int i = base + tid; i < lim; i += 512)
    atomicAdd(&h[((unsigned)dst[i]) >> LOG_NPB], 1);
  __syncthreads();
  for (int k = tid; k < nbk; k += 512) {
    cur[k] = 0;
    int v = h[k];
    int g = -1;
    if (v) {
      g = atomicAdd(&gcur[k], v);
      if (capb && (g + v > (k + 1) * capb)) g = -1;
    }
    gb[k] = g;
  }
  __syncthreads();
  for (int i = base + tid; i < lim; i += 512) {
    unsigned d = (unsigned)dst[i];
    unsigned k = d >> LOG_NPB;
    int pos = atomicAdd(&cur[k], 1);
    int g = gb[k];
    if (g >= 0)
      csr[g + pos] = make_uint2((unsigned)src[i] | ((d & (NPB - 1u)) << 20),
                                __float_as_uint(w[i]));
  }
}

__global__ __launch_bounds__(256) void gather_kernel(
    const float* __restrict__ x, const int* __restrict__ gbase,
    const int* __restrict__ gcur, const uint2* __restrict__ csr,
    float* __restrict__ out, int n_nodes, int capb,
    const int* __restrict__ src, const int* __restrict__ dst,
    const float* __restrict__ w, int n_edges) {
  __shared__ uint2 eds[CAP];
  __shared__ unsigned short perm[CAP];
  __shared__ int loff[NPB + 1];
  __shared__ int lcur[NPB];
  __shared__ int sh[9];

  const int b = blockIdx.x;
  const int tid = threadIdx.x;
  const int beg = capb ? b * capb : gbase[b];
  const int cnt = gcur[b] - beg;
  const int limcap = capb ? capb : CAP;
  const int nbase = b * NPB;

  const int wv = tid >> 6;
  const int lane = tid & 63;
  const int f = lane & 31;
  const int half = lane >> 5;
  const float4* X = (const float4*)x;

  if (cnt <= limcap) {
    if (tid < NPB) lcur[tid] = 0;
    __syncthreads();
    for (int i = tid; i < cnt; i += 256) {
      uint2 e = csr[beg + i];
      eds[i] = e;
      atomicAdd(&lcur[e.x >> 20], 1);
    }
    __syncthreads();
    {
      int v = (tid < NPB) ? lcur[tid] : 0;
      int ex = block_excl_scan(v, sh, nullptr);
      __syncthreads();
      if (tid < NPB) { loff[tid] = ex; lcur[tid] = 0; }
      if (tid == 0) loff[NPB] = cnt;
    }
    __syncthreads();
    for (int i = tid; i < cnt; i += 256) {
      int dl = eds[i].x >> 20;
      int pos = loff[dl] + atomicAdd(&lcur[dl], 1);
      perm[pos] = (unsigned short)i;
    }
    __syncthreads();

    for (int n = wv; n < NPB; n += 4) {
      int node = nbase + n;
      if (node >= n_nodes) break;
      int jb = loff[n];
      int je = loff[n + 1];
      float4 a0 = make_float4(0.f, 0.f, 0.f, 0.f);
      float4 a1 = make_float4(0.f, 0.f, 0.f, 0.f);
      float4 a2 = make_float4(0.f, 0.f, 0.f, 0.f);
      float4 a3 = make_float4(0.f, 0.f, 0.f, 0.f);
      int j = jb + half;
      for (; j + 6 < je; j += 8) {
        uint2 e0 = eds[perm[j]];
        uint2 e1 = eds[perm[j + 2]];
        uint2 e2 = eds[perm[j + 4]];
        uint2 e3 = eds[perm[j + 6]];
        float4 v0 = X[(size_t)(e0.x & 0xFFFFFu) * 32 + f];
        float4 v1 = X[(size_t)(e1.x & 0xFFFFFu) * 32 + f];
        float4 v2 = X[(size_t)(e2.x & 0xFFFFFu) * 32 + f];
        float4 v3 = X[(size_t)(e3.x & 0xFFFFFu) * 32 + f];
        float w0 = __uint_as_float(e0.y);
        float w1 = __uint_as_float(e1.y);
        float w2 = __uint_as_float(e2.y);
        float w3 = __uint_as_float(e3.y);
        a0.x += w0 * v0.x; a0.y += w0 * v0.y; a0.z += w0 * v0.z; a0.w += w0 * v0.w;
        a1.x += w1 * v1.x; a1.y += w1 * v1.y; a1.z += w1 * v1.z; a1.w += w1 * v1.w;
        a2.x += w2 * v2.x; a2.y += w2 * v2.y; a2.z += w2 * v2.z; a2.w += w2 * v2.w;
        a3.x += w3 * v3.x; a3.y += w3 * v3.y; a3.z += w3 * v3.z; a3.w += w3 * v3.w;
      }
      for (; j < je; j += 2) {
        uint2 e0 = eds[perm[j]];
        float4 v0 = X[(size_t)(e0.x & 0xFFFFFu) * 32 + f];
        float w0 = __uint_as_float(e0.y);
        a0.x += w0 * v0.x; a0.y += w0 * v0.y; a0.z += w0 * v0.z; a0.w += w0 * v0.w;
      }
      a0.x += a1.x + a2.x + a3.x;
      a0.y += a1.y + a2.y + a3.y;
      a0.z += a1.z + a2.z + a3.z;
      a0.w += a1.w + a2.w + a3.w;
      a0.x += __shfl_xor(a0.x, 32, 64);
      a0.y += __shfl_xor(a0.y, 32, 64);
      a0.z += __shfl_xor(a0.z, 32, 64);
      a0.w += __shfl_xor(a0.w, 32, 64);
      if (half == 0) {
        v4f val = {a0.x, a0.y, a0.z, a0.w};
        __builtin_nontemporal_store(val, (v4f*)out + (size_t)node * 32 + f);
      }
    }
  } else {
    for (int n = wv; n < NPB; n += 4) {
      int node = nbase + n;
      if (node >= n_nodes) break;
      float4 a0 = make_float4(0.f, 0.f, 0.f, 0.f);
      for (int j = half; j < n_edges; j += 2) {
        if (dst[j] == node) {
          float4 v = X[(size_t)src[j] * 32 + f];
          float wt = w[j];
          a0.x += wt * v.x; a0.y += wt * v.y; a0.z += wt * v.z; a0.w += wt * v.w;
        }
      }
      a0.x += __shfl_xor(a0.x, 32, 64);
      a0.y += __shfl_xor(a0.y, 32, 64);
      a0.z += __shfl_xor(a0.z, 32, 64);
      a0.w += __shfl_xor(a0.w, 32, 64);
      if (half == 0) {
        v4f val = {a0.x, a0.y, a0.z, a0.w};
        __builtin_nontemporal_store(val, (v4f*)out + (size_t)node * 32 + f);
      }
    }
  }
}

extern "C" void kernel_launch(void* const* d_in, const int* in_sizes, int n_in,
                              void* d_out, int out_size, void* d_ws, size_t ws_size,
                              hipStream_t stream) {
  const float* x  = (const float*)d_in[0];
  const float* w  = (const float*)d_in[1];
  const int* eidx = (const int*)d_in[2];

  int n_edges = in_sizes[1];           // E
  int n_nodes = out_size / D_FEAT;     // N
  const int* src = eidx;
  const int* dst = eidx + n_edges;
  float* out = (float*)d_out;

  if (n_edges <= 0) {
    hipMemsetAsync(d_out, 0, (size_t)out_size * sizeof(float), stream);
    return;
  }

  const int nbk = (n_nodes + NPB - 1) / NPB;       // buckets (782 @100K)
  const int ftile = (n_edges + nbk - 1) / nbk;     // fused per-block tile
  const int stile = (n_edges + SCB - 1) / SCB;     // separate-path tile

  // ws layout (ints): gtot[1024] | gcur[1024] | done[4] | gbase[1028] | csr
  const size_t ctrl_ints = (size_t)NBK_MAX + NBK_MAX + 4 + (NBK_MAX + 4);
  const size_t ctrl_bytes = ctrl_ints * 4;
  long long slots_avail = ((long long)ws_size - (long long)ctrl_bytes) / 8;

  long long mean = n_edges / (nbk > 0 ? nbk : 1);
  int capb_min = (int)(mean + 7.0 * sqrt((double)(mean > 0 ? mean : 1)) + 32);
  int capb = 0;
  if (nbk > 0 && slots_avail > 0) {
    long long c = slots_avail / nbk;
    if (c > CAP) c = CAP;
    capb = (int)(c & ~7LL);
  }
  bool seg_ok = (capb >= capb_min && capb_min <= CAP);
  bool exact_ok = (slots_avail >= (long long)n_edges);

  if ((!seg_ok && !exact_ok) || nbk > NBK_MAX || n_nodes >= (1 << 20)) {
    hipMemsetAsync(d_out, 0, (size_t)out_size * sizeof(float), stream);
    long long total_threads = (long long)n_edges * 32;
    long long grid = (total_threads + 255) / 256;
    scatter_atomic_kernel<<<(dim3)(unsigned)grid, 256, 0, stream>>>(
        x, w, src, dst, out, n_edges);
    return;
  }

  int* gtot = (int*)d_ws;                   // 1024
  int* gcur = gtot + NBK_MAX;               // 1024
  int* done = gcur + NBK_MAX;               // 4
  int* gbase = done + 4;                    // 1028 (nbk+1 used)
  uint2* csr = (uint2*)(gbase + NBK_MAX + 4);

  if (seg_ok) {
    // --- fused cooperative single-dispatch path ---
    int fe = n_edges, fn = n_nodes, fb = nbk, ft = ftile, fc = capb;
    void* kargs[] = {(void*)&x,    (void*)&w,   (void*)&src, (void*)&dst,
                     (void*)&gcur, (void*)&csr, (void*)&out, (void*)&fe,
                     (void*)&fn,   (void*)&fb,  (void*)&ft,  (void*)&fc};
    hipError_t err = hipLaunchCooperativeKernel(
        (void*)fused_kernel, dim3((unsigned)nbk), dim3(256), kargs, 0, stream);
    if (err == hipSuccess) return;
    // cooperative rejected -> R12 3-dispatch seg path
    init_seg_kernel<<<(nbk + 255) / 256, 256, 0, stream>>>(gcur, nbk, capb);
    scatter_kernel<<<SCB, 512, 0, stream>>>(src, dst, w, gcur, csr,
                                            n_edges, nbk, stile, capb);
    gather_kernel<<<nbk, 256, 0, stream>>>(x, gbase, gcur, csr, out, n_nodes,
                                           capb, src, dst, w, n_edges);
  } else {
    // exact-CSR path: memset -> hist(+prefix) -> scatter -> gather
    hipMemsetAsync(gtot, 0, (size_t)(NBK_MAX * 2 + 4) * sizeof(int), stream);
    hist_kernel<<<SCB, 512, 0, stream>>>(dst, gtot, gcur, gbase, done,
                                         n_edges, nbk, stile);
    scatter_kernel<<<SCB, 512, 0, stream>>>(src, dst, w, gcur, csr,
                                            n_edges, nbk, stile, 0);
    gather_kernel<<<nbk, 256, 0, stream>>>(x, gbase, gcur, csr, out, n_nodes,
                                           0, src, dst, w, n_edges);
  }
}

// Round 7
// 247.860 us; speedup vs baseline: 2.0075x; 2.0075x over previous
//
#include <hip/hip_runtime.h>
#include <math.h>

// LightGCN layer: out[v] = sum_{(u->v)} w * x[u], N=100K, E=1.6M, D=128, fp32.
//
// R15: R14's fused experiment measured the two missing constants:
//   - FIXED harness overhead ~87us (497 total - 410 fused kernel): the
//     "~126us front-end" chased in R10-R13 was mostly THIS, not our kernels.
//     Real scatter+init is only ~35us (R12: 254 = 87 + 128 gather + ~37).
//   - cross-XCD producer->consumer inside one kernel loses badly (csr dirty
//     lines + grid.sync acquire blows the L2 set: 1.2TB/s, VALU 5%).
// Therefore: revert to the R12 separate-dispatch structure (best: 254.3us),
// NPB=128 gather (proven 126.3-127.3us, rate-saturated at 3.4TB/s on 375MB
// of structural per-XCD row fills), and take the one low-risk lever left:
// scatter SCB 256->512 blocks (tile 3125, same LDS) for 2x CU coverage of
// the ~35us scatter. Dispatches: init -> scatter -> gather.

constexpr int D_FEAT = 128;
constexpr int NPB = 128;        // nodes per bucket (dst >> 7)
constexpr int LOG_NPB = 7;
constexpr int NBK_MAX = 1024;
constexpr int SCB = 512;        // scatter/hist block count
constexpr int CAP = 3072;       // max edges per bucket staged in gather LDS

typedef float v4f __attribute__((ext_vector_type(4)));

// ---------------- fallback (R1) ----------------
__global__ __launch_bounds__(256) void scatter_atomic_kernel(
    const float* __restrict__ x, const float* __restrict__ w,
    const int* __restrict__ src_idx, const int* __restrict__ dst_idx,
    float* __restrict__ out, int n_edges) {
  long long tid = (long long)blockIdx.x * blockDim.x + threadIdx.x;
  int lane = (int)(tid & 31);
  long long e = tid >> 5;
  if (e >= n_edges) return;
  int s = src_idx[e];
  int d = dst_idx[e];
  float wt = w[e];
  float4 v = ((const float4*)(x + (size_t)s * D_FEAT))[lane];
  float* o = out + (size_t)d * D_FEAT + (size_t)lane * 4;
  atomicAdd(o + 0, v.x * wt);
  atomicAdd(o + 1, v.y * wt);
  atomicAdd(o + 2, v.z * wt);
  atomicAdd(o + 3, v.w * wt);
}

// block-wide exclusive scan over blockDim.x threads (multiple of 64, <=512);
// sh holds >= (nwaves+1) ints (declare 9).
__device__ __forceinline__ int block_excl_scan(int v, int* sh, int* total) {
  const int lane = threadIdx.x & 63;
  const int wid = threadIdx.x >> 6;
  const int nw = blockDim.x >> 6;
  int inc = v;
  #pragma unroll
  for (int o = 1; o < 64; o <<= 1) {
    int t = __shfl_up(inc, o, 64);
    if (lane >= o) inc += t;
  }
  if (lane == 63) sh[wid] = inc;
  __syncthreads();
  if (threadIdx.x == 0) {
    int a = 0;
    for (int k = 0; k < nw; ++k) { int t = sh[k]; sh[k] = a; a += t; }
    sh[nw] = a;
  }
  __syncthreads();
  int r = sh[wid] + inc - v;
  if (total) *total = sh[nw];
  __syncthreads();
  return r;
}

// ---------------- exact path phase 1: global hist + in-kernel prefix -------
// gtot/gcur/done pre-zeroed by memset. Last block computes the exclusive
// prefix into gbase[0..nbk] and initializes gcur = gbase.
__global__ __launch_bounds__(512) void hist_kernel(
    const int* __restrict__ dst, int* __restrict__ gtot,
    int* __restrict__ gcur, int* __restrict__ gbase, int* __restrict__ done,
    int n_edges, int nbk, int tile) {
  __shared__ int h[NBK_MAX];
  __shared__ int sh[9];
  __shared__ int slast;
  const int tid = threadIdx.x;
  const int b = blockIdx.x;
  for (int k = tid; k < nbk; k += 512) h[k] = 0;
  __syncthreads();
  int base = b * tile;
  int lim = min(base + tile, n_edges);
  for (int i = base + tid; i < lim; i += 512)
    atomicAdd(&h[((unsigned)dst[i]) >> LOG_NPB], 1);
  __syncthreads();
  for (int k = tid; k < nbk; k += 512)
    if (h[k]) atomicAdd(&gtot[k], h[k]);
  __threadfence();
  __syncthreads();
  if (tid == 0)
    slast = (__hip_atomic_fetch_add(done, 1, __ATOMIC_ACQ_REL,
                                    __HIP_MEMORY_SCOPE_AGENT) ==
             (int)gridDim.x - 1);
  __syncthreads();
  if (slast) {
    int carry = 0;
    for (int kb = 0; kb < nbk; kb += 512) {
      int k = kb + tid;
      int v = (k < nbk)
                  ? __hip_atomic_load(&gtot[k], __ATOMIC_RELAXED,
                                      __HIP_MEMORY_SCOPE_AGENT)
                  : 0;
      int tot;
      int ex = block_excl_scan(v, sh, &tot);
      if (k < nbk) { gbase[k] = carry + ex; gcur[k] = carry + ex; }
      carry += tot;
    }
    if (tid == 0) gbase[nbk] = carry;
  }
}

// ---------------- segment path init: gcur[k] = k*capb ----------------------
__global__ __launch_bounds__(256) void init_seg_kernel(int* __restrict__ gcur,
                                                       int nbk, int capb) {
  int k = blockIdx.x * 256 + threadIdx.x;
  if (k < nbk) gcur[k] = k * capb;
}

// ---------------- phase 2: scatter (LDS tile-hist + run reservation) -------
// pass1: LDS hist of the tile; reserve per-bucket runs with ONE global
// atomicAdd per non-empty bucket; pass2: re-read (L2-warm) and place via LDS
// cursors. capb != 0 => segment mode: runs that would cross the segment end
// are dropped (gb=-1); gather then sees cnt > capb -> raw-scan fallback.
__global__ __launch_bounds__(512) void scatter_kernel(
    const int* __restrict__ src, const int* __restrict__ dst,
    const float* __restrict__ w, int* __restrict__ gcur,
    uint2* __restrict__ csr, int n_edges, int nbk, int tile, int capb) {
  __shared__ int h[NBK_MAX];
  __shared__ int cur[NBK_MAX];
  __shared__ int gb[NBK_MAX];
  const int tid = threadIdx.x;
  const int b = blockIdx.x;
  int base = b * tile;
  int lim = min(base + tile, n_edges);
  for (int k = tid; k < nbk; k += 512) h[k] = 0;
  __syncthreads();
  for (int i = base + tid; i < lim; i += 512)
    atomicAdd(&h[((unsigned)dst[i]) >> LOG_NPB], 1);
  __syncthreads();
  for (int k = tid; k < nbk; k += 512) {
    cur[k] = 0;
    int v = h[k];
    int g = -1;
    if (v) {
      g = atomicAdd(&gcur[k], v);
      if (capb && (g + v > (k + 1) * capb)) g = -1;  // overflow (P ~ 1e-6)
    }
    gb[k] = g;
  }
  __syncthreads();
  for (int i = base + tid; i < lim; i += 512) {
    unsigned d = (unsigned)dst[i];
    unsigned k = d >> LOG_NPB;
    int pos = atomicAdd(&cur[k], 1);
    int g = gb[k];
    if (g >= 0)
      csr[g + pos] = make_uint2((unsigned)src[i] | ((d & (NPB - 1u)) << 20),
                                __float_as_uint(w[i]));
  }
}

// ---------------- phase 3: gather (LDS perm-sort + register accumulate) ----
// Frozen (R8/R12/R13-proven): rate-saturated at ~3.4 TB/s on ~375MB of
// structural per-XCD random 512B row fills; occupancy is NOT the limiter
// (R12: 57% occ, same BW).
__global__ __launch_bounds__(256) void gather_kernel(
    const float* __restrict__ x, const int* __restrict__ gbase,
    const int* __restrict__ gcur, const uint2* __restrict__ csr,
    float* __restrict__ out, int n_nodes, int capb,
    const int* __restrict__ src, const int* __restrict__ dst,
    const float* __restrict__ w, int n_edges) {
  __shared__ uint2 eds[CAP];            // 24 KB staged edges
  __shared__ unsigned short perm[CAP];  // 6 KB sorted order
  __shared__ int loff[NPB + 1];
  __shared__ int lcur[NPB];
  __shared__ int sh[9];

  const int b = blockIdx.x;
  const int tid = threadIdx.x;
  const int beg = capb ? b * capb : gbase[b];
  const int cnt = gcur[b] - beg;
  const int limcap = capb ? capb : CAP;
  const int nbase = b * NPB;

  const int wv = tid >> 6;
  const int lane = tid & 63;
  const int f = lane & 31;
  const int half = lane >> 5;
  const float4* X = (const float4*)x;

  if (cnt <= limcap) {
    // stage + local hist
    if (tid < NPB) lcur[tid] = 0;
    __syncthreads();
    for (int i = tid; i < cnt; i += 256) {
      uint2 e = csr[beg + i];
      eds[i] = e;
      atomicAdd(&lcur[e.x >> 20], 1);
    }
    __syncthreads();
    // scan 128 counters -> loff, reset lcur as cursor
    {
      int v = (tid < NPB) ? lcur[tid] : 0;
      int ex = block_excl_scan(v, sh, nullptr);
      __syncthreads();
      if (tid < NPB) { loff[tid] = ex; lcur[tid] = 0; }
      if (tid == 0) loff[NPB] = cnt;
    }
    __syncthreads();
    // build perm (counting-sort placement)
    for (int i = tid; i < cnt; i += 256) {
      int dl = eds[i].x >> 20;
      int pos = loff[dl] + atomicAdd(&lcur[dl], 1);
      perm[pos] = (unsigned short)i;
    }
    __syncthreads();

    // register-accumulate per node (1 wave/node, 2 halves x unroll4)
    for (int n = wv; n < NPB; n += 4) {
      int node = nbase + n;
      if (node >= n_nodes) break;
      int jb = loff[n];
      int je = loff[n + 1];
      float4 a0 = make_float4(0.f, 0.f, 0.f, 0.f);
      float4 a1 = make_float4(0.f, 0.f, 0.f, 0.f);
      float4 a2 = make_float4(0.f, 0.f, 0.f, 0.f);
      float4 a3 = make_float4(0.f, 0.f, 0.f, 0.f);
      int j = jb + half;
      for (; j + 6 < je; j += 8) {
        uint2 e0 = eds[perm[j]];
        uint2 e1 = eds[perm[j + 2]];
        uint2 e2 = eds[perm[j + 4]];
        uint2 e3 = eds[perm[j + 6]];
        float4 v0 = X[(size_t)(e0.x & 0xFFFFFu) * 32 + f];
        float4 v1 = X[(size_t)(e1.x & 0xFFFFFu) * 32 + f];
        float4 v2 = X[(size_t)(e2.x & 0xFFFFFu) * 32 + f];
        float4 v3 = X[(size_t)(e3.x & 0xFFFFFu) * 32 + f];
        float w0 = __uint_as_float(e0.y);
        float w1 = __uint_as_float(e1.y);
        float w2 = __uint_as_float(e2.y);
        float w3 = __uint_as_float(e3.y);
        a0.x += w0 * v0.x; a0.y += w0 * v0.y; a0.z += w0 * v0.z; a0.w += w0 * v0.w;
        a1.x += w1 * v1.x; a1.y += w1 * v1.y; a1.z += w1 * v1.z; a1.w += w1 * v1.w;
        a2.x += w2 * v2.x; a2.y += w2 * v2.y; a2.z += w2 * v2.z; a2.w += w2 * v2.w;
        a3.x += w3 * v3.x; a3.y += w3 * v3.y; a3.z += w3 * v3.z; a3.w += w3 * v3.w;
      }
      for (; j < je; j += 2) {
        uint2 e0 = eds[perm[j]];
        float4 v0 = X[(size_t)(e0.x & 0xFFFFFu) * 32 + f];
        float w0 = __uint_as_float(e0.y);
        a0.x += w0 * v0.x; a0.y += w0 * v0.y; a0.z += w0 * v0.z; a0.w += w0 * v0.w;
      }
      a0.x += a1.x + a2.x + a3.x;
      a0.y += a1.y + a2.y + a3.y;
      a0.z += a1.z + a2.z + a3.z;
      a0.w += a1.w + a2.w + a3.w;
      a0.x += __shfl_xor(a0.x, 32, 64);
      a0.y += __shfl_xor(a0.y, 32, 64);
      a0.z += __shfl_xor(a0.z, 32, 64);
      a0.w += __shfl_xor(a0.w, 32, 64);
      if (half == 0) {
        v4f val = {a0.x, a0.y, a0.z, a0.w};
        __builtin_nontemporal_store(val, (v4f*)out + (size_t)node * 32 + f);
      }
    }
  } else {
    // safety net (statistically unreachable; covers segment overflow):
    // scan the RAW edge list for this bucket's nodes.
    for (int n = wv; n < NPB; n += 4) {
      int node = nbase + n;
      if (node >= n_nodes) break;
      float4 a0 = make_float4(0.f, 0.f, 0.f, 0.f);
      for (int j = half; j < n_edges; j += 2) {
        if (dst[j] == node) {
          float4 v = X[(size_t)src[j] * 32 + f];
          float wt = w[j];
          a0.x += wt * v.x; a0.y += wt * v.y; a0.z += wt * v.z; a0.w += wt * v.w;
        }
      }
      a0.x += __shfl_xor(a0.x, 32, 64);
      a0.y += __shfl_xor(a0.y, 32, 64);
      a0.z += __shfl_xor(a0.z, 32, 64);
      a0.w += __shfl_xor(a0.w, 32, 64);
      if (half == 0) {
        v4f val = {a0.x, a0.y, a0.z, a0.w};
        __builtin_nontemporal_store(val, (v4f*)out + (size_t)node * 32 + f);
      }
    }
  }
}

extern "C" void kernel_launch(void* const* d_in, const int* in_sizes, int n_in,
                              void* d_out, int out_size, void* d_ws, size_t ws_size,
                              hipStream_t stream) {
  const float* x  = (const float*)d_in[0];
  const float* w  = (const float*)d_in[1];
  const int* eidx = (const int*)d_in[2];

  int n_edges = in_sizes[1];           // E
  int n_nodes = out_size / D_FEAT;     // N
  const int* src = eidx;
  const int* dst = eidx + n_edges;
  float* out = (float*)d_out;

  if (n_edges <= 0) {
    hipMemsetAsync(d_out, 0, (size_t)out_size * sizeof(float), stream);
    return;
  }

  const int nbk = (n_nodes + NPB - 1) / NPB;       // buckets (782 @100K)
  const int stile = (n_edges + SCB - 1) / SCB;     // edges per scatter block

  // ws layout (ints): gtot[1024] | gcur[1024] | done[4] | gbase[1028] | csr
  const size_t ctrl_ints = (size_t)NBK_MAX + NBK_MAX + 4 + (NBK_MAX + 4);
  const size_t ctrl_bytes = ctrl_ints * 4;
  long long slots_avail = ((long long)ws_size - (long long)ctrl_bytes) / 8;

  long long mean = n_edges / (nbk > 0 ? nbk : 1);
  int capb_min = (int)(mean + 7.0 * sqrt((double)(mean > 0 ? mean : 1)) + 32);
  int capb = 0;
  if (nbk > 0 && slots_avail > 0) {
    long long c = slots_avail / nbk;
    if (c > CAP) c = CAP;
    capb = (int)(c & ~7LL);
  }
  bool seg_ok = (capb >= capb_min && capb_min <= CAP);
  bool exact_ok = (slots_avail >= (long long)n_edges);

  if ((!seg_ok && !exact_ok) || nbk > NBK_MAX || n_nodes >= (1 << 20)) {
    hipMemsetAsync(d_out, 0, (size_t)out_size * sizeof(float), stream);
    long long total_threads = (long long)n_edges * 32;
    long long grid = (total_threads + 255) / 256;
    scatter_atomic_kernel<<<(dim3)(unsigned)grid, 256, 0, stream>>>(
        x, w, src, dst, out, n_edges);
    return;
  }

  int* gtot = (int*)d_ws;                   // 1024
  int* gcur = gtot + NBK_MAX;               // 1024
  int* done = gcur + NBK_MAX;               // 4
  int* gbase = done + 4;                    // 1028 (nbk+1 used)
  uint2* csr = (uint2*)(gbase + NBK_MAX + 4);

  if (seg_ok) {
    // 3 dispatches: init -> scatter -> gather
    init_seg_kernel<<<(nbk + 255) / 256, 256, 0, stream>>>(gcur, nbk, capb);
    scatter_kernel<<<SCB, 512, 0, stream>>>(src, dst, w, gcur, csr,
                                            n_edges, nbk, stile, capb);
    gather_kernel<<<nbk, 256, 0, stream>>>(x, gbase, gcur, csr, out, n_nodes,
                                           capb, src, dst, w, n_edges);
  } else {
    // exact-CSR path: memset -> hist(+prefix) -> scatter -> gather
    hipMemsetAsync(gtot, 0, (size_t)(NBK_MAX * 2 + 4) * sizeof(int), stream);
    hist_kernel<<<SCB, 512, 0, stream>>>(dst, gtot, gcur, gbase, done,
                                         n_edges, nbk, stile);
    scatter_kernel<<<SCB, 512, 0, stream>>>(src, dst, w, gcur, csr,
                                            n_edges, nbk, stile, 0);
    gather_kernel<<<nbk, 256, 0, stream>>>(x, gbase, gcur, csr, out, n_nodes,
                                           0, src, dst, w, n_edges);
  }
}